// Round 1
// baseline (83.375 us; speedup 1.0000x reference)
//
#include <hip/hip_runtime.h>

// R12 structure — 3 dispatches, no device fences:
//   sort_rows (128 blk) : label ranks + permute rows to sorted fp16 + norms
//                         (widened from 16 blk; wave-reduced ranks/norms)
//   main      (256 blk) : per-block G rows i0,i1 via MFMA from sorted F16
//                         (replaces standalone gram kernel; L2-resident B reads),
//                         then e, wave scans, exact binsearch denom
//   finalize  (1 blk)   : reduce 256 partials
// Measured regressions to avoid: ticket+threadfence finalize (+3us, R11),
// 2-kernel merge with orig-order Gram (+5.5us, R9), cooperative grid.sync
// (+90us, R10), fp16 phase-1 in main (+4us, R6), in-loop norms (+11us, R5).

#define N 512          // n = 2*B
#define B 256
#define D 512
#define NT 512         // block size for sort/main
#define NBLK (N / 2)   // 256 main blocks, 2 rows each

// ws layout (float offsets)
#define WS_SL    0                    // [N] sorted labels ascending
#define WS_NORM  512                  // [N] ||f16||^2 (fp32) by sorted position
#define WS_PART  1024                 // [NBLK] per-block partial sums
#define WS_FH    2048                 // N*D _Float16 sorted features (512 KB)

typedef _Float16 half4_t  __attribute__((ext_vector_type(4)));
typedef _Float16 half8_t  __attribute__((ext_vector_type(8)));
typedef float    f32x4    __attribute__((ext_vector_type(4)));

// ---- kernel 1 (grid 128): ranks + permute 4 rows/block to sorted fp16 ----
__global__ __launch_bounds__(NT) void sort_rows_kernel(
    const float* __restrict__ wt, const float* __restrict__ mt,
    const float* __restrict__ lwt, const float* __restrict__ lmt,
    float* __restrict__ ws)
{
    const int t = threadIdx.x, b = blockIdx.x;   // b in [0,128)
    __shared__ float slab[N];
    __shared__ int scnt[4];
    __shared__ float swred[NT / 64];
    slab[t] = (t < B) ? lwt[t] : lmt[t - B];
    if (t < 4) scnt[t] = 0;
    __syncthreads();

    // rank of row j = b*4 + jj; jj = t>>7 (two waves per row group),
    // each thread scans 4 labels, wave-reduce, 2 atomics per counter
    const int jj = t >> 7, j = b * 4 + jj;
    const int c = t & 127;
    const float lj = slab[j];
    int r = 0;
    #pragma unroll
    for (int x = c * 4; x < c * 4 + 4; ++x) {
        const float v = slab[x];
        r += (v < lj || (v == lj && x < j)) ? 1 : 0;
    }
    #pragma unroll
    for (int off = 32; off > 0; off >>= 1)
        r += __shfl_down(r, off, 64);
    if ((t & 63) == 0) atomicAdd(&scnt[jj], r);
    __syncthreads();

    if (t < 4)
        ws[WS_SL + scnt[t]] = slab[b * 4 + t];

    // permute: 128 threads per row, one float4 each; norms of rounded fp16
    const int rr = scnt[jj];                     // sorted position of row j
    const float* F = (j < B) ? (wt + (size_t)j * D) : (mt + (size_t)(j - B) * D);
    const float4 v = ((const float4*)F)[c];
    half4_t h;
    h[0] = (_Float16)v.x; h[1] = (_Float16)v.y;
    h[2] = (_Float16)v.z; h[3] = (_Float16)v.w;
    ((half4_t*)((_Float16*)(ws + WS_FH) + (size_t)rr * D))[c] = h;
    const float f0 = (float)h[0], f1 = (float)h[1];
    const float f2 = (float)h[2], f3 = (float)h[3];
    float nacc = f0 * f0 + f1 * f1 + f2 * f2 + f3 * f3;
    #pragma unroll
    for (int off = 32; off > 0; off >>= 1)
        nacc += __shfl_down(nacc, off, 64);
    if ((t & 63) == 0) swred[t >> 6] = nacc;
    __syncthreads();
    if (t < 4)
        ws[WS_NORM + scnt[t]] = swred[2 * t] + swred[2 * t + 1];
}

// ---- kernel 2 (grid 256): fused G-rows (MFMA) + e + scan + binsearch ----
__global__ __launch_bounds__(NT) void rnc_main(float* __restrict__ ws)
{
    const int b = blockIdx.x, i0 = 2 * b, i1 = 2 * b + 1;  // sorted positions
    const int t = threadIdx.x;
    const int w = t >> 6, lane = t & 63;

    __shared__ float sl[N];
    __shared__ float snm[N];
    __shared__ __align__(16) float sp0[N];
    __shared__ __align__(16) float sf0[N];
    __shared__ __align__(16) float sp1[N];
    __shared__ __align__(16) float sf1[N];
    __shared__ float sg0[N];
    __shared__ float sg1[N];
    __shared__ float sred[NT / 64];

    sl[t]  = ws[WS_SL + t];
    snm[t] = ws[WS_NORM + t];

    // ---- phase 0: G rows i0,i1 via MFMA from sorted fp16 (L2-resident) ----
    // A-frag rows: m&1 -> {i0,i1} broadcast; D rows 2..15 are redundant.
    // C/D layout: col = lane&15, row = quad*4 + reg -> quad==0, reg 0/1 hold
    // G[i0][col], G[i1][col]. Same MFMA + k-order as old gram kernel ->
    // bit-identical G values.
    const _Float16* Fh = (const _Float16*)(ws + WS_FH);
    const int quad = lane >> 4, m = lane & 15;
    const _Float16* Ap = Fh + (size_t)(i0 + (m & 1)) * D + quad * 8;
    const _Float16* Bp[4];
    #pragma unroll
    for (int u = 0; u < 4; ++u)
        Bp[u] = Fh + (size_t)((w * 4 + u) * 16 + m) * D + quad * 8;

    f32x4 acc[4] = {{0.f,0.f,0.f,0.f},{0.f,0.f,0.f,0.f},
                    {0.f,0.f,0.f,0.f},{0.f,0.f,0.f,0.f}};
    #pragma unroll
    for (int k0 = 0; k0 < D; k0 += 32) {
        const half8_t a = *(const half8_t*)(Ap + k0);
        #pragma unroll
        for (int u = 0; u < 4; ++u) {
            const half8_t bb = *(const half8_t*)(Bp[u] + k0);
            acc[u] = __builtin_amdgcn_mfma_f32_16x16x32_f16(a, bb, acc[u], 0, 0, 0);
        }
    }
    if (quad == 0) {
        #pragma unroll
        for (int u = 0; u < 4; ++u) {
            const int col = w * 64 + u * 16 + m;   // 16 consecutive floats/group
            sg0[col] = acc[u][0];
            sg1[col] = acc[u][1];
        }
    }
    __syncthreads();

    const float li0 = sl[i0], li1 = sl[i1];
    const float ni0 = snm[i0], ni1 = snm[i1];

    // ---- phase 1: e from in-block Gram rows ----
    const float g0 = sg0[t];
    const float g1 = sg1[t];
    const float d0 = fmaxf(ni0 + snm[t] - 2.f * g0, 0.f);
    const float d1 = fmaxf(ni1 + snm[t] - 2.f * g1, 0.f);
    const float lg0 = -0.5f * sqrtf(d0);
    const float lg1 = -0.5f * sqrtf(d1);
    float lg_acc = 0.f;
    if (t != i0) lg_acc += lg0;
    if (t != i1) lg_acc += lg1;
    const float e0 = (t == i0) ? 0.f : __expf(lg0);
    const float e1 = (t == i1) ? 0.f : __expf(lg1);
    sp0[t] = e0; sf0[t] = e0;
    sp1[t] = e1; sf1[t] = e1;
    __syncthreads();

    // ---- phase 2a: wave-parallel scans (no block barriers inside) ----
    if (w < 4) {
        float* arr = (w == 0) ? sp0 : (w == 1) ? sf0 : (w == 2) ? sp1 : sf1;
        float4* a4 = (float4*)arr;
        float4 u0 = a4[lane * 2], u1 = a4[lane * 2 + 1];
        float v0 = u0.x, v1 = u0.y, v2 = u0.z, v3 = u0.w;
        float v4 = u1.x, v5 = u1.y, v6 = u1.z, v7 = u1.w;
        if ((w & 1) == 0) {                    // inclusive prefix scan
            v1 += v0; v2 += v1; v3 += v2; v4 += v3; v5 += v4; v6 += v5; v7 += v6;
            float x = v7;
            #pragma unroll
            for (int off = 1; off < 64; off <<= 1) {
                const float y = __shfl_up(x, off, 64);
                if (lane >= off) x += y;
            }
            float ex = __shfl_up(x, 1, 64);
            if (lane == 0) ex = 0.f;
            v0 += ex; v1 += ex; v2 += ex; v3 += ex; v4 += ex; v5 += ex; v6 += ex; v7 += ex;
        } else {                               // inclusive suffix scan
            v6 += v7; v5 += v6; v4 += v5; v3 += v4; v2 += v3; v1 += v2; v0 += v1;
            float x = v0;
            #pragma unroll
            for (int off = 1; off < 64; off <<= 1) {
                const float y = __shfl_down(x, off, 64);
                if (lane + off < 64) x += y;
            }
            float ex = __shfl_down(x, 1, 64);
            if (lane == 63) ex = 0.f;
            v0 += ex; v1 += ex; v2 += ex; v3 += ex; v4 += ex; v5 += ex; v6 += ex; v7 += ex;
        }
        a4[lane * 2]     = make_float4(v0, v1, v2, v3);
        a4[lane * 2 + 1] = make_float4(v4, v5, v6, v7);
    }
    __syncthreads();

    // ---- phase 2b: per-k denom via two exact binary searches (ri == i) ----
    float local = lg_acc;
    #pragma unroll
    for (int p = 0; p < 2; ++p) {
        const int x = t;                      // sorted position of k
        const int ri = p ? i1 : i0;
        const float li = p ? li1 : li0;
        const float* SP = p ? sp1 : sp0;
        const float* SF = p ? sf1 : sf0;
        if (x != ri) {
            const float th = fabsf(li - sl[x]);
            int lo = 0, hi = ri + 1;          // left branch: weakly decreasing
            while (lo < hi) {
                const int mid = (lo + hi) >> 1;
                if (fabsf(li - sl[mid]) >= th) lo = mid + 1; else hi = mid;
            }
            const int a = lo;
            lo = ri + 1; hi = N;              // right branch: weakly increasing
            while (lo < hi) {
                const int mid = (lo + hi) >> 1;
                if (fabsf(li - sl[mid]) >= th) hi = mid; else lo = mid + 1;
            }
            const int bb = lo;
            const float denom = ((a > 0) ? SP[a - 1] : 0.f) + ((bb < N) ? SF[bb] : 0.f);
            local -= __logf(denom);
        }
    }

    // ---- block reduction, plain store ----
    #pragma unroll
    for (int off = 32; off > 0; off >>= 1)
        local += __shfl_down(local, off, 64);
    if (lane == 0) sred[w] = local;
    __syncthreads();
    if (t == 0) {
        float sum = 0.f;
        #pragma unroll
        for (int k = 0; k < NT / 64; ++k) sum += sred[k];
        ws[WS_PART + b] = sum;
    }
}

// ---- kernel 3: reduce 256 partials + finalize ----
__global__ __launch_bounds__(NBLK) void rnc_finalize(
    const float* __restrict__ ws, float* __restrict__ out)
{
    const int t = threadIdx.x;
    __shared__ float sred[NBLK / 64];
    float v = ws[WS_PART + t];
    #pragma unroll
    for (int off = 32; off > 0; off >>= 1)
        v += __shfl_down(v, off, 64);
    if ((t & 63) == 0) sred[t >> 6] = v;
    __syncthreads();
    if (t == 0) {
        float sum = 0.f;
        #pragma unroll
        for (int k = 0; k < NBLK / 64; ++k) sum += sred[k];
        out[0] = -sum / (float)((long)N * (N - 1));
    }
}

extern "C" void kernel_launch(void* const* d_in, const int* in_sizes, int n_in,
                              void* d_out, int out_size, void* d_ws, size_t ws_size,
                              hipStream_t stream) {
    const float* wt  = (const float*)d_in[0];
    const float* mt  = (const float*)d_in[1];
    const float* lwt = (const float*)d_in[2];
    const float* lmt = (const float*)d_in[3];
    float* out = (float*)d_out;
    float* ws  = (float*)d_ws;

    sort_rows_kernel<<<128, NT, 0, stream>>>(wt, mt, lwt, lmt, ws);
    rnc_main<<<NBLK, NT, 0, stream>>>(ws);
    rnc_finalize<<<1, NBLK, 0, stream>>>(ws, out);
}

// Round 3
// 76.151 us; speedup vs baseline: 1.0949x; 1.0949x over previous
//
#include <hip/hip_runtime.h>

// R13 — 4 dispatches (R8 structure restored), no device fences:
//   sort_rows (128 blk) : label ranks + permute rows to sorted fp16 + norms
//                         (widened from 16 blk, verified in R12)
//   gram      (64 blk)  : MFMA f16 Gram, 32x32 tile/wave (2x2 accs) — halves
//                         A/B read traffic vs 16x16/wave; bit-identical G
//   main      (256 blk) : e from G rows, wave scans, exact binsearch denom
//   finalize  (1 blk)   : reduce 256 partials
// Measured regressions to avoid: fused per-block G-rows-in-main (+8us, R12:
// 128MB redundant L3 traffic on main's critical path), ticket+threadfence
// finalize (+3us, R11), 2-kernel merge with orig-order Gram (+5.5us, R9),
// cooperative grid.sync (+90us, R10), fp16 phase-1 in main (+4us, R6),
// in-loop norms (+11us, R5).

#define N 512          // n = 2*B
#define B 256
#define D 512
#define NT 512         // block size for sort/main
#define NBLK (N / 2)   // 256 main blocks, 2 rows each

// ws layout (float offsets)
#define WS_SL    0                    // [N] sorted labels ascending
#define WS_NORM  512                  // [N] ||f16||^2 (fp32) by sorted position
#define WS_PART  1024                 // [NBLK] per-block partial sums
#define WS_FH    2048                 // N*D _Float16 sorted features (512 KB)
#define WS_G     (2048 + (N * D) / 2) // [N*N] fp32 Gram matrix (1 MB)

typedef _Float16 half4_t  __attribute__((ext_vector_type(4)));
typedef _Float16 half8_t  __attribute__((ext_vector_type(8)));
typedef float    f32x4    __attribute__((ext_vector_type(4)));

// ---- kernel 1 (grid 128): ranks + permute 4 rows/block to sorted fp16 ----
__global__ __launch_bounds__(NT) void sort_rows_kernel(
    const float* __restrict__ wt, const float* __restrict__ mt,
    const float* __restrict__ lwt, const float* __restrict__ lmt,
    float* __restrict__ ws)
{
    const int t = threadIdx.x, b = blockIdx.x;   // b in [0,128)
    __shared__ float slab[N];
    __shared__ int scnt[4];
    __shared__ float swred[NT / 64];
    slab[t] = (t < B) ? lwt[t] : lmt[t - B];
    if (t < 4) scnt[t] = 0;
    __syncthreads();

    // rank of row j = b*4 + jj; jj = t>>7 (two waves per row group),
    // each thread scans 4 labels, wave-reduce, 2 atomics per counter
    const int jj = t >> 7, j = b * 4 + jj;
    const int c = t & 127;
    const float lj = slab[j];
    int r = 0;
    #pragma unroll
    for (int x = c * 4; x < c * 4 + 4; ++x) {
        const float v = slab[x];
        r += (v < lj || (v == lj && x < j)) ? 1 : 0;
    }
    #pragma unroll
    for (int off = 32; off > 0; off >>= 1)
        r += __shfl_down(r, off, 64);
    if ((t & 63) == 0) atomicAdd(&scnt[jj], r);
    __syncthreads();

    if (t < 4)
        ws[WS_SL + scnt[t]] = slab[b * 4 + t];

    // permute: 128 threads per row, one float4 each; norms of rounded fp16
    const int rr = scnt[jj];                     // sorted position of row j
    const float* F = (j < B) ? (wt + (size_t)j * D) : (mt + (size_t)(j - B) * D);
    const float4 v = ((const float4*)F)[c];
    half4_t h;
    h[0] = (_Float16)v.x; h[1] = (_Float16)v.y;
    h[2] = (_Float16)v.z; h[3] = (_Float16)v.w;
    ((half4_t*)((_Float16*)(ws + WS_FH) + (size_t)rr * D))[c] = h;
    const float f0 = (float)h[0], f1 = (float)h[1];
    const float f2 = (float)h[2], f3 = (float)h[3];
    float nacc = f0 * f0 + f1 * f1 + f2 * f2 + f3 * f3;
    #pragma unroll
    for (int off = 32; off > 0; off >>= 1)
        nacc += __shfl_down(nacc, off, 64);
    if ((t & 63) == 0) swred[t >> 6] = nacc;
    __syncthreads();
    if (t < 4)
        ws[WS_NORM + scnt[t]] = swred[2 * t] + swred[2 * t + 1];
}

// ---- kernel 2 (grid 64 x 256thr): MFMA Gram, 32x32 tile per wave ----
// 2x2 accumulators: 4 loads feed 4 MFMAs per k-step (vs 2:1 at 16x16/wave),
// halving A/B read traffic. Per-output k-order identical to 16x16 version ->
// bit-identical G. C/D layout (H1, verified): col = lane&15, row = quad*4+reg.
__global__ __launch_bounds__(256) void gram_kernel(float* __restrict__ ws)
{
    const int lane = threadIdx.x & 63;
    const int wid  = blockIdx.x * 4 + (threadIdx.x >> 6);   // 0..255
    const int ti = wid >> 4, tj = wid & 15;                 // 32x32 tile coords
    const int quad = lane >> 4, m = lane & 15;

    const _Float16* Fh = (const _Float16*)(ws + WS_FH);
    const _Float16* A0 = Fh + (size_t)(ti * 32 + m) * D + quad * 8;
    const _Float16* A1 = A0 + (size_t)16 * D;
    const _Float16* B0 = Fh + (size_t)(tj * 32 + m) * D + quad * 8;
    const _Float16* B1 = B0 + (size_t)16 * D;

    f32x4 acc00 = {0.f, 0.f, 0.f, 0.f};
    f32x4 acc01 = {0.f, 0.f, 0.f, 0.f};
    f32x4 acc10 = {0.f, 0.f, 0.f, 0.f};
    f32x4 acc11 = {0.f, 0.f, 0.f, 0.f};
    #pragma unroll
    for (int k0 = 0; k0 < D; k0 += 32) {
        const half8_t a0 = *(const half8_t*)(A0 + k0);
        const half8_t a1 = *(const half8_t*)(A1 + k0);
        const half8_t b0 = *(const half8_t*)(B0 + k0);
        const half8_t b1 = *(const half8_t*)(B1 + k0);
        acc00 = __builtin_amdgcn_mfma_f32_16x16x32_f16(a0, b0, acc00, 0, 0, 0);
        acc01 = __builtin_amdgcn_mfma_f32_16x16x32_f16(a0, b1, acc01, 0, 0, 0);
        acc10 = __builtin_amdgcn_mfma_f32_16x16x32_f16(a1, b0, acc10, 0, 0, 0);
        acc11 = __builtin_amdgcn_mfma_f32_16x16x32_f16(a1, b1, acc11, 0, 0, 0);
    }
    float* G = ws + WS_G;
    const int r0 = ti * 32 + quad * 4;
    const int c0 = tj * 32 + m;
    #pragma unroll
    for (int rg = 0; rg < 4; ++rg) {
        G[(size_t)(r0 + rg) * N + c0]           = acc00[rg];
        G[(size_t)(r0 + rg) * N + c0 + 16]      = acc01[rg];
        G[(size_t)(r0 + 16 + rg) * N + c0]      = acc10[rg];
        G[(size_t)(r0 + 16 + rg) * N + c0 + 16] = acc11[rg];
    }
}

// ---- kernel 3 (grid 256): 2 rows/block; e from G, scan, binsearch ----
__global__ __launch_bounds__(NT) void rnc_main(float* __restrict__ ws)
{
    const int b = blockIdx.x, i0 = 2 * b, i1 = 2 * b + 1;  // sorted positions
    const int t = threadIdx.x;
    const int w = t >> 6, lane = t & 63;

    __shared__ float sl[N];
    __shared__ float snm[N];
    __shared__ __align__(16) float sp0[N];
    __shared__ __align__(16) float sf0[N];
    __shared__ __align__(16) float sp1[N];
    __shared__ __align__(16) float sf1[N];
    __shared__ float sred[NT / 64];

    sl[t]  = ws[WS_SL + t];
    snm[t] = ws[WS_NORM + t];
    __syncthreads();
    const float li0 = sl[i0], li1 = sl[i1];
    const float ni0 = snm[i0], ni1 = snm[i1];

    // ---- phase 1: e from precomputed Gram rows (coalesced 4 KB total) ----
    const float* G = ws + WS_G;
    const float g0 = G[(size_t)i0 * N + t];
    const float g1 = G[(size_t)i1 * N + t];
    const float d0 = fmaxf(ni0 + snm[t] - 2.f * g0, 0.f);
    const float d1 = fmaxf(ni1 + snm[t] - 2.f * g1, 0.f);
    const float lg0 = -0.5f * sqrtf(d0);
    const float lg1 = -0.5f * sqrtf(d1);
    float lg_acc = 0.f;
    if (t != i0) lg_acc += lg0;
    if (t != i1) lg_acc += lg1;
    const float e0 = (t == i0) ? 0.f : __expf(lg0);
    const float e1 = (t == i1) ? 0.f : __expf(lg1);
    sp0[t] = e0; sf0[t] = e0;
    sp1[t] = e1; sf1[t] = e1;
    __syncthreads();

    // ---- phase 2a: wave-parallel scans (no block barriers inside) ----
    if (w < 4) {
        float* arr = (w == 0) ? sp0 : (w == 1) ? sf0 : (w == 2) ? sp1 : sf1;
        float4* a4 = (float4*)arr;
        float4 u0 = a4[lane * 2], u1 = a4[lane * 2 + 1];
        float v0 = u0.x, v1 = u0.y, v2 = u0.z, v3 = u0.w;
        float v4 = u1.x, v5 = u1.y, v6 = u1.z, v7 = u1.w;
        if ((w & 1) == 0) {                    // inclusive prefix scan
            v1 += v0; v2 += v1; v3 += v2; v4 += v3; v5 += v4; v6 += v5; v7 += v6;
            float x = v7;
            #pragma unroll
            for (int off = 1; off < 64; off <<= 1) {
                const float y = __shfl_up(x, off, 64);
                if (lane >= off) x += y;
            }
            float ex = __shfl_up(x, 1, 64);
            if (lane == 0) ex = 0.f;
            v0 += ex; v1 += ex; v2 += ex; v3 += ex; v4 += ex; v5 += ex; v6 += ex; v7 += ex;
        } else {                               // inclusive suffix scan
            v6 += v7; v5 += v6; v4 += v5; v3 += v4; v2 += v3; v1 += v2; v0 += v1;
            float x = v0;
            #pragma unroll
            for (int off = 1; off < 64; off <<= 1) {
                const float y = __shfl_down(x, off, 64);
                if (lane + off < 64) x += y;
            }
            float ex = __shfl_down(x, 1, 64);
            if (lane == 63) ex = 0.f;
            v0 += ex; v1 += ex; v2 += ex; v3 += ex; v4 += ex; v5 += ex; v6 += ex; v7 += ex;
        }
        a4[lane * 2]     = make_float4(v0, v1, v2, v3);
        a4[lane * 2 + 1] = make_float4(v4, v5, v6, v7);
    }
    __syncthreads();

    // ---- phase 2b: per-k denom via two exact binary searches (ri == i) ----
    float local = lg_acc;
    #pragma unroll
    for (int p = 0; p < 2; ++p) {
        const int x = t;                      // sorted position of k
        const int ri = p ? i1 : i0;
        const float li = p ? li1 : li0;
        const float* SP = p ? sp1 : sp0;
        const float* SF = p ? sf1 : sf0;
        if (x != ri) {
            const float th = fabsf(li - sl[x]);
            int lo = 0, hi = ri + 1;          // left branch: weakly decreasing
            while (lo < hi) {
                const int mid = (lo + hi) >> 1;
                if (fabsf(li - sl[mid]) >= th) lo = mid + 1; else hi = mid;
            }
            const int a = lo;
            lo = ri + 1; hi = N;              // right branch: weakly increasing
            while (lo < hi) {
                const int mid = (lo + hi) >> 1;
                if (fabsf(li - sl[mid]) >= th) hi = mid; else lo = mid + 1;
            }
            const int bb = lo;
            const float denom = ((a > 0) ? SP[a - 1] : 0.f) + ((bb < N) ? SF[bb] : 0.f);
            local -= __logf(denom);
        }
    }

    // ---- block reduction, plain store ----
    #pragma unroll
    for (int off = 32; off > 0; off >>= 1)
        local += __shfl_down(local, off, 64);
    if (lane == 0) sred[w] = local;
    __syncthreads();
    if (t == 0) {
        float sum = 0.f;
        #pragma unroll
        for (int k = 0; k < NT / 64; ++k) sum += sred[k];
        ws[WS_PART + b] = sum;
    }
}

// ---- kernel 4: reduce 256 partials + finalize ----
__global__ __launch_bounds__(NBLK) void rnc_finalize(
    const float* __restrict__ ws, float* __restrict__ out)
{
    const int t = threadIdx.x;
    __shared__ float sred[NBLK / 64];
    float v = ws[WS_PART + t];
    #pragma unroll
    for (int off = 32; off > 0; off >>= 1)
        v += __shfl_down(v, off, 64);
    if ((t & 63) == 0) sred[t >> 6] = v;
    __syncthreads();
    if (t == 0) {
        float sum = 0.f;
        #pragma unroll
        for (int k = 0; k < NBLK / 64; ++k) sum += sred[k];
        out[0] = -sum / (float)((long)N * (N - 1));
    }
}

extern "C" void kernel_launch(void* const* d_in, const int* in_sizes, int n_in,
                              void* d_out, int out_size, void* d_ws, size_t ws_size,
                              hipStream_t stream) {
    const float* wt  = (const float*)d_in[0];
    const float* mt  = (const float*)d_in[1];
    const float* lwt = (const float*)d_in[2];
    const float* lmt = (const float*)d_in[3];
    float* out = (float*)d_out;
    float* ws  = (float*)d_ws;

    sort_rows_kernel<<<128, NT, 0, stream>>>(wt, mt, lwt, lmt, ws);
    gram_kernel<<<64, 256, 0, stream>>>(ws);
    rnc_main<<<NBLK, NT, 0, stream>>>(ws);
    rnc_finalize<<<1, NBLK, 0, stream>>>(ws, out);
}